// Round 6
// baseline (369.700 us; speedup 1.0000x reference)
//
#include <hip/hip_runtime.h>
#include <cstdint>
#include <cstddef>

#define NH 16
#define ND 64
#define NK 256
#define NE 8
#define NV 196608
#define NBL 16384           // B*L = 4*4096
#define TOK 64              // tokens per block
#define MROW 17             // means LDS row stride in float4 (272B)
#define ACC_STRIDE 257

struct Primes { int p[NH]; };

// ---------------- K1: PQ assignment + EMA accumulation + normed_x ----------------
// 512 threads: c = tid&31 (cluster col; cl = i*32+c), r = tid>>5 (token row; 4 tokens each)
// Tile: 4 tok x 8 cl = 32 acc regs; x double-buffered for pipelining (~85 regs total).
__global__ __launch_bounds__(512, 2) void k_pq(
    const float* __restrict__ x, const float* __restrict__ means,
    const float* __restrict__ lnxs, const float* __restrict__ lnxb,
    float* __restrict__ out, uint8_t* __restrict__ cids,
    float* __restrict__ gsum, int* __restrict__ gcnt)
{
  // LDS: sm4 17408f | smsq2 512f | scnt 256i | sactive 256i | snact 1i = 73732B
  __shared__ __align__(16) float smem[18433];
  float4* sm4     = (float4*)smem;               // [256 cl][17] (slots 0..15 used)
  float*  smsq2   = smem + 17408;                // [2][256]
  int*    scnt    = (int*)(smem + 17920);        // [256]
  int*    sactive = (int*)(smem + 18176);        // [256]
  int*    snact   = (int*)(smem + 18432);        // [1]
  float*  accum   = smem;                        // phase 2: [64 d][257] = 16448 f

  const int tid = threadIdx.x;
  const int c   = tid & 31;
  const int r   = tid >> 5;
  const int h   = blockIdx.y;
  const int g0  = blockIdx.x * TOK;

  // ---- stage means: thread stages half-row (cl = tid&255, hf = tid>>8) ----
  {
    const int cl = tid & 255, hf = tid >> 8;
    const float4* src = (const float4*)(means + ((size_t)h * NK + cl) * ND + hf * 32);
    float mp = 0.f;
#pragma unroll
    for (int i = 0; i < 8; ++i) {
      float4 v = src[i];
      sm4[cl * MROW + hf * 8 + i] = v;
      mp += v.x * v.x + v.y * v.y + v.z * v.z + v.w * v.w;
    }
    smsq2[hf * NK + cl] = mp;
    if (tid < NK) scnt[tid] = 0;
    if (tid == 0) *snact = 0;
  }
  __syncthreads();

  // ---- distance GEMM: acc[j][i] = dot(x[token r*4+j], means[i*32+c]) ----
  float acc[4][8];
#pragma unroll
  for (int j = 0; j < 4; ++j)
#pragma unroll
    for (int i = 0; i < 8; ++i) acc[j][i] = 0.f;

  const float* xb = x + ((size_t)(g0 + r * 4) * NH + h) * ND;   // token stride 1024 f

  float4 cur[4];
#pragma unroll
  for (int j = 0; j < 4; ++j) cur[j] = *(const float4*)(xb + (size_t)j * (NH * ND));

#pragma unroll 4
  for (int dc = 0; dc < 16; ++dc) {
    float4 nxt[4];
    if (dc + 1 < 16) {
#pragma unroll
      for (int j = 0; j < 4; ++j)
        nxt[j] = *(const float4*)(xb + (size_t)j * (NH * ND) + (dc + 1) * 4);
    }
#pragma unroll
    for (int i = 0; i < 8; ++i) {
      float4 mv = sm4[(i * 32 + c) * MROW + dc];
#pragma unroll
      for (int j = 0; j < 4; ++j) {
        float a = acc[j][i];
        a = fmaf(cur[j].x, mv.x, a);
        a = fmaf(cur[j].y, mv.y, a);
        a = fmaf(cur[j].z, mv.z, a);
        a = fmaf(cur[j].w, mv.w, a);
        acc[j][i] = a;
      }
    }
    if (dc + 1 < 16) {
#pragma unroll
      for (int j = 0; j < 4; ++j) cur[j] = nxt[j];
    }
  }

  // ---- argmin (dist = msq - 2*dot; x_sq constant per token), tie-break smallest id ----
  int bk[4];
  {
    float bv[4]; int bi_[4];
#pragma unroll
    for (int j = 0; j < 4; ++j) { bv[j] = 3.4e38f; bi_[j] = 0; }
#pragma unroll
    for (int i = 0; i < 8; ++i) {
      const int cl = i * 32 + c;
      const float mq = smsq2[cl] + smsq2[NK + cl];
#pragma unroll
      for (int j = 0; j < 4; ++j) {
        float d = mq - 2.0f * acc[j][i];
        if (d < bv[j]) { bv[j] = d; bi_[j] = cl; }
      }
    }
#pragma unroll
    for (int j = 0; j < 4; ++j) {
      float v = bv[j]; int id = bi_[j];
#pragma unroll
      for (int m = 1; m < 32; m <<= 1) {
        float ov = __shfl_xor(v, m);
        int   oi = __shfl_xor(id, m);
        if (ov < v || (ov == v && oi < id)) { v = ov; id = oi; }
      }
      bk[j] = id;
    }
    if (c == 0) {
#pragma unroll
      for (int j = 0; j < 4; ++j) {
        cids[(size_t)(g0 + r * 4 + j) * NH + h] = (uint8_t)bk[j];
        atomicAdd(&scnt[bk[j]], 1);
      }
    }
  }

  __syncthreads();                               // scnt final; sm4/smsq reads done

  // ---- zero accum + build active-cluster list ----
  for (int idx = tid; idx < ND * ACC_STRIDE; idx += 512) accum[idx] = 0.f;
  if (tid < NK) {
    const int cnt = scnt[tid];
    if (cnt > 0) {
      int p = atomicAdd(snact, 1);
      sactive[p] = tid;
      atomicAdd(&gcnt[h * NK + tid], cnt);
    }
  }
  __syncthreads();

  // ---- EMA accumulate: lane (c,r): d = 2c,2c+1 for its 4 tokens ----
#pragma unroll
  for (int j = 0; j < 4; ++j) {
    float2 v = *(const float2*)(x + ((size_t)(g0 + r * 4 + j) * NH + h) * ND + c * 2);
    atomicAdd(&accum[(c * 2 + 0) * ACC_STRIDE + bk[j]], v.x);
    atomicAdd(&accum[(c * 2 + 1) * ACC_STRIDE + bk[j]], v.y);
  }

  // ---- normed_x -> out[0:56): thread = (token tl = tid>>3, octant q = tid&7) ----
  {
    const int tl = tid >> 3, q = tid & 7;
    const float* xt = x + ((size_t)(g0 + tl) * NH + h) * ND + q * 8;
    float4 v0 = *(const float4*)(xt);
    float4 v1 = *(const float4*)(xt + 4);
    float s  = v0.x + v0.y + v0.z + v0.w + v1.x + v1.y + v1.z + v1.w;
    float sq = v0.x * v0.x + v0.y * v0.y + v0.z * v0.z + v0.w * v0.w
             + v1.x * v1.x + v1.y * v1.y + v1.z * v1.z + v1.w * v1.w;
    s  += __shfl_xor(s, 1);  sq += __shfl_xor(sq, 1);
    s  += __shfl_xor(s, 2);  sq += __shfl_xor(sq, 2);
    s  += __shfl_xor(s, 4);  sq += __shfl_xor(sq, 4);
    float mu  = s * (1.f / 64.f);
    float var = sq * (1.f / 64.f) - mu * mu;
    float rs  = rsqrtf(var + 1e-5f);
    if (q < 7) {
      float4 s0 = *(const float4*)(lnxs + h * ND + q * 8);
      float4 s1 = *(const float4*)(lnxs + h * ND + q * 8 + 4);
      float4 b0 = *(const float4*)(lnxb + h * ND + q * 8);
      float4 b1 = *(const float4*)(lnxb + h * ND + q * 8 + 4);
      float4 o0, o1;
      o0.x = (v0.x - mu) * rs * s0.x + b0.x;
      o0.y = (v0.y - mu) * rs * s0.y + b0.y;
      o0.z = (v0.z - mu) * rs * s0.z + b0.z;
      o0.w = (v0.w - mu) * rs * s0.w + b0.w;
      o1.x = (v1.x - mu) * rs * s1.x + b1.x;
      o1.y = (v1.y - mu) * rs * s1.y + b1.y;
      o1.z = (v1.z - mu) * rs * s1.z + b1.z;
      o1.w = (v1.w - mu) * rs * s1.w + b1.w;
      float* orow = out + ((size_t)(g0 + tl) * NH + h) * ND + q * 8;
      *(float4*)(orow)     = o0;
      *(float4*)(orow + 4) = o1;
    }
  }
  __syncthreads();

  // ---- flush via active list: 8 groups of 64 d-lanes; gsum [h][k][d] coalesced ----
  {
    const int d = tid & 63, grp = tid >> 6;
    const int nact = *snact;
    for (int a = grp; a < nact; a += 8) {
      const int cl = sactive[a];
      atomicAdd(&gsum[(((size_t)h << 8) + cl) * ND + d], accum[d * ACC_STRIDE + cl]);
    }
  }
}

// ---------------- K2: bigram hash + embedding gather + LN_y -> out[56:64) ----------------
__global__ __launch_bounds__(256) void k_ngram(
    const uint8_t* __restrict__ cids, const float* __restrict__ embed,
    const float* __restrict__ lys, const float* __restrict__ lyb,
    float* __restrict__ out, Primes pr)
{
  const int i = blockIdx.x * 256 + threadIdx.x;  // 0 .. NBL*NH-1
  const int h = i & 15;
  const int g = i >> 4;
  const int l = g & 4095;                        // L = 4096

  int cid  = (int)cids[i];
  int prev = (l == 0) ? 0 : (int)cids[i - NH];
  int ng   = cid + (prev << 8);
  int hp1  = h + 1;
  int v    = ng * hp1 + hp1;
  const int p = pr.p[h];
  while (v >= p) v -= p;
  if (v >= NV) v -= NV;

  const float4* e4 = (const float4*)(embed + ((size_t)(v + NV * h)) * NE);
  float4 y0 = e4[0], y1 = e4[1];

  float s = ((y0.x + y0.y) + (y0.z + y0.w)) + ((y1.x + y1.y) + (y1.z + y1.w));
  float mu = s * 0.125f;
  float q = y0.x * y0.x + y0.y * y0.y + y0.z * y0.z + y0.w * y0.w
          + y1.x * y1.x + y1.y * y1.y + y1.z * y1.z + y1.w * y1.w;
  float var = q * 0.125f - mu * mu;
  float rs  = rsqrtf(var + 1e-5f);

  const float* sc = lys + h * NE;
  const float* bi = lyb + h * NE;
  float4 o0, o1;
  o0.x = (y0.x - mu) * rs * sc[0] + bi[0];
  o0.y = (y0.y - mu) * rs * sc[1] + bi[1];
  o0.z = (y0.z - mu) * rs * sc[2] + bi[2];
  o0.w = (y0.w - mu) * rs * sc[3] + bi[3];
  o1.x = (y1.x - mu) * rs * sc[4] + bi[4];
  o1.y = (y1.y - mu) * rs * sc[5] + bi[5];
  o1.z = (y1.z - mu) * rs * sc[6] + bi[6];
  o1.w = (y1.w - mu) * rs * sc[7] + bi[7];

  float4* orow = (float4*)(out + ((size_t)g * NH + h) * ND + 56);
  orow[0] = o0;
  orow[1] = o1;
}

// ---------------- K3: finalize new_means (gsum [h][k][d] = same flat order as means) ----------------
__global__ __launch_bounds__(256) void k_means(
    const float* __restrict__ means, const float* __restrict__ gsum,
    const int* __restrict__ gcnt, float* __restrict__ newm)
{
  const int i = blockIdx.x * 256 + threadIdx.x;  // flat [h][k][d]
  float cnt = (float)gcnt[i >> 6];
  float mx  = gsum[i] / (1e-6f + cnt);
  newm[i] = 0.001f * mx + 0.999f * means[i];
}

extern "C" void kernel_launch(void* const* d_in, const int* in_sizes, int n_in,
                              void* d_out, int out_size, void* d_ws, size_t ws_size,
                              hipStream_t stream)
{
  const float* x     = (const float*)d_in[0];
  const float* means = (const float*)d_in[1];
  const float* embed = (const float*)d_in[2];
  const float* lnxs  = (const float*)d_in[3];
  const float* lnxb  = (const float*)d_in[4];
  const float* lys   = (const float*)d_in[5];
  const float* lyb   = (const float*)d_in[6];

  float* out  = (float*)d_out;
  float* newm = out + (size_t)NBL * NH * ND;

  float*   gsum = (float*)d_ws;
  int*     gcnt = (int*)((char*)d_ws + (size_t)NH * NK * ND * 4);
  uint8_t* cids = (uint8_t*)((char*)d_ws + (size_t)NH * NK * ND * 4 + (size_t)NH * NK * 4);

  hipMemsetAsync(d_ws, 0, (size_t)NH * NK * ND * 4 + (size_t)NH * NK * 4, stream);

  Primes pr;
  {
    int n = NV, c = 0;
    while (c < NH) {
      ++n;
      bool isp = true;
      for (int q = 2; (long long)q * q <= n; ++q)
        if (n % q == 0) { isp = false; break; }
      if (isp) pr.p[c++] = n;
    }
  }

  dim3 g1(NBL / TOK, NH);
  k_pq<<<g1, 512, 0, stream>>>(x, means, lnxs, lnxb, out, cids, gsum, gcnt);
  k_ngram<<<(NBL * NH) / 256, 256, 0, stream>>>(cids, embed, lys, lyb, out, pr);
  k_means<<<(NH * NK * ND) / 256, 256, 0, stream>>>(means, gsum, gcnt, newm);
}

// Round 7
// 314.445 us; speedup vs baseline: 1.1757x; 1.1757x over previous
//
#include <hip/hip_runtime.h>
#include <cstdint>
#include <cstddef>

#define NH 16
#define ND 64
#define NK 256
#define NE 8
#define NV 196608
#define NBL 16384           // B*L = 4*4096
#define TOK 128             // tokens per block
#define XS4 129             // xT row stride in float4 (padded: column reads 2-way)
#define ACC_STRIDE 257

struct Primes { int p[NH]; };

// ---------------- K1: PQ assignment + EMA accumulation + normed_x ----------------
// 512 threads; GEMM tile: r = tid>>5 (8 tokens each), c = tid&31 (8 clusters each, cl = i*32+c).
// All GEMM operands in LDS (d-major); no global loads inside the dc loop.
__global__ __launch_bounds__(512, 1) void k_pq(
    const float* __restrict__ x, const float* __restrict__ means,
    const float* __restrict__ lnxs, const float* __restrict__ lnxb,
    float* __restrict__ out, uint8_t* __restrict__ cids,
    float* __restrict__ gsum, int* __restrict__ gcnt)
{
  // floats: xT [16][XS4] f4 = 8256 | mT [16][256] f4 = 16384 | smsq2 512 | scnt 256 | sactive 256 | snact 1
  __shared__ __align__(16) float smem[25668];
  float4* xT4     = (float4*)smem;                    // [16 dc][XS4] (slots 0..127 used)
  float4* mT4     = (float4*)(smem + 8256);           // [16 dc][256 cl]
  float*  smsq2   = smem + 24640;                     // [2][256]
  int*    scnt    = (int*)(smem + 25152);             // [256]
  int*    sactive = (int*)(smem + 25408);             // [256]
  int*    snact   = (int*)(smem + 25664);
  float*  accum   = smem + 8256;                      // phase 2: [64 d][257] = 16448 f (over mT)

  const int tid = threadIdx.x;
  const int c   = tid & 31;
  const int r   = tid >> 5;
  const int h   = blockIdx.y;
  const int g0  = blockIdx.x * TOK;

  // ---- stage means d-major (contiguous 128B per thread, perfectly coalesced) ----
  {
    const int cl = tid >> 1, d0 = (tid & 1) * 8;      // 8*t = cl*16 + d0
    const float4* src = (const float4*)means + ((size_t)h * NK) * 16 + (size_t)tid * 8;
    float mp = 0.f;
#pragma unroll
    for (int j = 0; j < 8; ++j) {
      float4 v = src[j];
      mT4[(d0 + j) * NK + cl] = v;
      mp += v.x * v.x + v.y * v.y + v.z * v.z + v.w * v.w;
    }
    smsq2[(tid & 1) * NK + cl] = mp;
  }
  // ---- stage x d-major: thread (tok = tid>>2, qd = tid&3) reads 64B contiguous ----
  {
    const int tok = tid >> 2, qd = tid & 3;
    const float4* src = (const float4*)(x + ((size_t)(g0 + tok) * NH + h) * ND) + qd * 4;
#pragma unroll
    for (int j = 0; j < 4; ++j)
      xT4[(qd * 4 + j) * XS4 + tok] = src[j];
  }
  if (tid < NK) scnt[tid] = 0;
  if (tid == 0) *snact = 0;
  __syncthreads();

  // ---- distance GEMM: acc[j][i] = dot(x[token r*8+j], means[i*32+c]) ----
  float acc[8][8];
#pragma unroll
  for (int j = 0; j < 8; ++j)
#pragma unroll
    for (int i = 0; i < 8; ++i) acc[j][i] = 0.f;

#pragma unroll 2
  for (int dc = 0; dc < 16; ++dc) {
    float4 xv[8];
#pragma unroll
    for (int j = 0; j < 8; ++j) xv[j] = xT4[dc * XS4 + r * 8 + j];   // broadcast (2 addrs/wave)
#pragma unroll
    for (int i = 0; i < 8; ++i) {
      float4 mv = mT4[dc * NK + i * 32 + c];                          // consecutive f4: optimal
#pragma unroll
      for (int j = 0; j < 8; ++j) {
        float a = acc[j][i];
        a = fmaf(xv[j].x, mv.x, a);
        a = fmaf(xv[j].y, mv.y, a);
        a = fmaf(xv[j].z, mv.z, a);
        a = fmaf(xv[j].w, mv.w, a);
        acc[j][i] = a;
      }
    }
  }

  // ---- argmin (dist = msq - 2*dot; x_sq constant per token), tie-break smallest id ----
  int bk[8];
  {
    float bv[8]; int bi_[8];
#pragma unroll
    for (int j = 0; j < 8; ++j) { bv[j] = 3.4e38f; bi_[j] = 0; }
#pragma unroll
    for (int i = 0; i < 8; ++i) {
      const int cl = i * 32 + c;
      const float mq = smsq2[cl] + smsq2[NK + cl];
#pragma unroll
      for (int j = 0; j < 8; ++j) {
        float d = mq - 2.0f * acc[j][i];
        if (d < bv[j]) { bv[j] = d; bi_[j] = cl; }
      }
    }
#pragma unroll
    for (int j = 0; j < 8; ++j) {
      float v = bv[j]; int id = bi_[j];
#pragma unroll
      for (int m = 1; m < 32; m <<= 1) {                // stays within 32-lane halves
        float ov = __shfl_xor(v, m);
        int   oi = __shfl_xor(id, m);
        if (ov < v || (ov == v && oi < id)) { v = ov; id = oi; }
      }
      bk[j] = id;
    }
    if (c == 0) {
#pragma unroll
      for (int j = 0; j < 8; ++j) {
        cids[(size_t)(g0 + r * 8 + j) * NH + h] = (uint8_t)bk[j];
        atomicAdd(&scnt[bk[j]], 1);
      }
    }
  }

  __syncthreads();                                     // GEMM LDS reads done; scnt final

  // ---- zero accum (over mT) + build active-cluster list ----
  for (int idx = tid; idx < ND * ACC_STRIDE; idx += 512) accum[idx] = 0.f;
  if (tid < NK) {
    const int cnt = scnt[tid];
    if (cnt > 0) {
      int p = atomicAdd(snact, 1);
      sactive[p] = tid;
      atomicAdd(&gcnt[h * NK + tid], cnt);
    }
  }
  __syncthreads();

  // ---- EMA accumulate from xT: lane (c,r): d = 2c,2c+1 for its 8 tokens ----
#pragma unroll
  for (int j = 0; j < 8; ++j) {
    const int tok = r * 8 + j;
    const float* xs = smem + (c >> 1) * (XS4 * 4) + tok * 4 + (c & 1) * 2;
    float vx = xs[0], vy = xs[1];
    atomicAdd(&accum[(c * 2 + 0) * ACC_STRIDE + bk[j]], vx);
    atomicAdd(&accum[(c * 2 + 1) * ACC_STRIDE + bk[j]], vy);
  }

  // ---- normed_x from xT -> out[0:56): thread (tok = tid>>2, q = tid&3) ----
  {
    const int tok = tid >> 2, q = tid & 3;
    float4 v[4];
    float s = 0.f, sq = 0.f;
#pragma unroll
    for (int j = 0; j < 4; ++j) {
      v[j] = xT4[(q * 4 + j) * XS4 + tok];
      s  += v[j].x + v[j].y + v[j].z + v[j].w;
      sq += v[j].x * v[j].x + v[j].y * v[j].y + v[j].z * v[j].z + v[j].w * v[j].w;
    }
    s  += __shfl_xor(s, 1);  sq += __shfl_xor(sq, 1);
    s  += __shfl_xor(s, 2);  sq += __shfl_xor(sq, 2);
    float mu  = s * (1.f / 64.f);
    float var = sq * (1.f / 64.f) - mu * mu;
    float rs  = rsqrtf(var + 1e-5f);
    float* orow = out + ((size_t)(g0 + tok) * NH + h) * ND + q * 16;
#pragma unroll
    for (int j = 0; j < 4; ++j) {
      const int d = q * 16 + j * 4;
      if (d < 56) {
        float4 sc = *(const float4*)(lnxs + h * ND + d);
        float4 bi = *(const float4*)(lnxb + h * ND + d);
        float4 o;
        o.x = (v[j].x - mu) * rs * sc.x + bi.x;
        o.y = (v[j].y - mu) * rs * sc.y + bi.y;
        o.z = (v[j].z - mu) * rs * sc.z + bi.z;
        o.w = (v[j].w - mu) * rs * sc.w + bi.w;
        *(float4*)(orow + j * 4) = o;
      }
    }
  }
  __syncthreads();

  // ---- flush via active list: 8 groups of 64 d-lanes; gsum [h][k][d] coalesced ----
  {
    const int d = tid & 63, grp = tid >> 6;
    const int nact = *snact;
    for (int a = grp; a < nact; a += 8) {
      const int cl = sactive[a];
      atomicAdd(&gsum[(((size_t)h << 8) + cl) * ND + d], accum[d * ACC_STRIDE + cl]);
    }
  }
}

// ---------------- K2: bigram hash + embedding gather + LN_y -> out[56:64) ----------------
__global__ __launch_bounds__(256) void k_ngram(
    const uint8_t* __restrict__ cids, const float* __restrict__ embed,
    const float* __restrict__ lys, const float* __restrict__ lyb,
    float* __restrict__ out, Primes pr)
{
  const int i = blockIdx.x * 256 + threadIdx.x;  // 0 .. NBL*NH-1
  const int h = i & 15;
  const int g = i >> 4;
  const int l = g & 4095;                        // L = 4096

  int cid  = (int)cids[i];
  int prev = (l == 0) ? 0 : (int)cids[i - NH];
  int ng   = cid + (prev << 8);
  int hp1  = h + 1;
  int v    = ng * hp1 + hp1;
  const int p = pr.p[h];
  while (v >= p) v -= p;
  if (v >= NV) v -= NV;

  const float4* e4 = (const float4*)(embed + ((size_t)(v + NV * h)) * NE);
  float4 y0 = e4[0], y1 = e4[1];

  float s = ((y0.x + y0.y) + (y0.z + y0.w)) + ((y1.x + y1.y) + (y1.z + y1.w));
  float mu = s * 0.125f;
  float q = y0.x * y0.x + y0.y * y0.y + y0.z * y0.z + y0.w * y0.w
          + y1.x * y1.x + y1.y * y1.y + y1.z * y1.z + y1.w * y1.w;
  float var = q * 0.125f - mu * mu;
  float rs  = rsqrtf(var + 1e-5f);

  const float* sc = lys + h * NE;
  const float* bi = lyb + h * NE;
  float4 o0, o1;
  o0.x = (y0.x - mu) * rs * sc[0] + bi[0];
  o0.y = (y0.y - mu) * rs * sc[1] + bi[1];
  o0.z = (y0.z - mu) * rs * sc[2] + bi[2];
  o0.w = (y0.w - mu) * rs * sc[3] + bi[3];
  o1.x = (y1.x - mu) * rs * sc[4] + bi[4];
  o1.y = (y1.y - mu) * rs * sc[5] + bi[5];
  o1.z = (y1.z - mu) * rs * sc[6] + bi[6];
  o1.w = (y1.w - mu) * rs * sc[7] + bi[7];

  float4* orow = (float4*)(out + ((size_t)g * NH + h) * ND + 56);
  orow[0] = o0;
  orow[1] = o1;
}

// ---------------- K3: finalize new_means (gsum [h][k][d] = same flat order as means) ----------------
__global__ __launch_bounds__(256) void k_means(
    const float* __restrict__ means, const float* __restrict__ gsum,
    const int* __restrict__ gcnt, float* __restrict__ newm)
{
  const int i = blockIdx.x * 256 + threadIdx.x;  // flat [h][k][d]
  float cnt = (float)gcnt[i >> 6];
  float mx  = gsum[i] / (1e-6f + cnt);
  newm[i] = 0.001f * mx + 0.999f * means[i];
}

extern "C" void kernel_launch(void* const* d_in, const int* in_sizes, int n_in,
                              void* d_out, int out_size, void* d_ws, size_t ws_size,
                              hipStream_t stream)
{
  const float* x     = (const float*)d_in[0];
  const float* means = (const float*)d_in[1];
  const float* embed = (const float*)d_in[2];
  const float* lnxs  = (const float*)d_in[3];
  const float* lnxb  = (const float*)d_in[4];
  const float* lys   = (const float*)d_in[5];
  const float* lyb   = (const float*)d_in[6];

  float* out  = (float*)d_out;
  float* newm = out + (size_t)NBL * NH * ND;

  float*   gsum = (float*)d_ws;
  int*     gcnt = (int*)((char*)d_ws + (size_t)NH * NK * ND * 4);
  uint8_t* cids = (uint8_t*)((char*)d_ws + (size_t)NH * NK * ND * 4 + (size_t)NH * NK * 4);

  hipMemsetAsync(d_ws, 0, (size_t)NH * NK * ND * 4 + (size_t)NH * NK * 4, stream);

  Primes pr;
  {
    int n = NV, c = 0;
    while (c < NH) {
      ++n;
      bool isp = true;
      for (int q = 2; (long long)q * q <= n; ++q)
        if (n % q == 0) { isp = false; break; }
      if (isp) pr.p[c++] = n;
    }
  }

  dim3 g1(NBL / TOK, NH);
  k_pq<<<g1, 512, 0, stream>>>(x, means, lnxs, lnxb, out, cids, gsum, gcnt);
  k_ngram<<<(NBL * NH) / 256, 256, 0, stream>>>(cids, embed, lys, lyb, out, pr);
  k_means<<<(NH * NK * ND) / 256, 256, 0, stream>>>(means, gsum, gcnt, newm);
}